// Round 1
// baseline (2209.454 us; speedup 1.0000x reference)
//
#include <hip/hip_runtime.h>
#include <stdint.h>

typedef unsigned short u16;
typedef unsigned int   u32;
typedef __attribute__((ext_vector_type(4)))  short s4v;
typedef __attribute__((ext_vector_type(8)))  short s8v;
typedef __attribute__((ext_vector_type(16))) float f16v;
typedef __attribute__((ext_vector_type(2)))  float f2v;

#define JJ 17
#define CC 128
#define BB 7            // batch elems per block
#define ROWS (BB*JJ)    // 119
#define PP 128          // padded rows (4 M-tiles of 32)
#define XPITCH 132      // ushort pitch for xh/xl (bank-conflict-free)
#define WLOP 20         // k-pitch (elems) in wlo chunks
#define NLAYERS 5

// LDS: xh(33792B) xl(33792B) h1(65536B) wlo(20480B) diag8(512B) bias(512B)
#define SMEM_BYTES 154624

__device__ __forceinline__ u16 f2bf(float f) {
  u32 u = __float_as_uint(f);
  u += 0x7FFFu + ((u >> 16) & 1u);   // RNE
  return (u16)(u >> 16);
}
__device__ __forceinline__ float bf2f(u16 h) {
  return __uint_as_float(((u32)h) << 16);
}
__device__ __forceinline__ s8v cmb(s4v a, s4v b) {
  s8v r;
  r[0]=a[0]; r[1]=a[1]; r[2]=a[2]; r[3]=a[3];
  r[4]=b[0]; r[5]=b[1]; r[6]=b[2]; r[7]=b[3];
  return r;
}
__device__ __forceinline__ float wred(float v) {
  #pragma unroll
  for (int m = 32; m >= 1; m >>= 1) v += __shfl_xor(v, m, 64);
  return v;
}

__global__ void __launch_bounds__(512, 2)
gconv_fused(const float* __restrict__ x, const float* __restrict__ x0,
            const float* __restrict__ adj, const float* __restrict__ W0,
            const float* __restrict__ W1, const float* __restrict__ bvec,
            const float* __restrict__ gamma, const float* __restrict__ beta,
            float* __restrict__ out, int Btot)
{
  extern __shared__ char smem[];
  u16*   xh    = (u16*)smem;                 // [PP][XPITCH] bf16 hi of x
  u16*   xl    = xh + PP*XPITCH;             // lo
  float* h1    = (float*)(xl + PP*XPITCH);   // [PP][CC] f32 (W-bounce at init; H1/M1 per layer)
  u16*   wlo   = (u16*)(h1 + PP*CC);         // [2 dbuf][2 W][128 n][WLOP] bf16 lo of W chunk
  float* diag8 = (float*)(wlo + 2*2*128*WLOP); // [128] 0.8*adj[j][j] per padded row
  float* biasl = diag8 + 128;                // [128]

  const int tid  = threadIdx.x;
  const int lane = tid & 63;
  const int wid  = tid >> 6;         // 0..7
  const int wm   = wid >> 2;         // 0..1  (M half)
  const int wn   = wid & 3;          // 0..3  (N tile of 32)
  const int g    = lane >> 5;        // k-subgroup
  const int nl   = lane & 31;
  const int ccol = wn*32 + nl;       // this lane's output column
  const int bg0  = blockIdx.x * BB;

  // ---- x0 into registers, accumulator layout, packed bf16 pairs ----
  u32 x0p[2][8];
  #pragma unroll
  for (int mt = 0; mt < 2; ++mt) {
    #pragma unroll
    for (int qp = 0; qp < 8; ++qp) {
      u32 pk = 0;
      #pragma unroll
      for (int h = 0; h < 2; ++h) {
        int q = qp*2 + h;
        int row = (wm*2+mt)*32 + (q&3) + 8*(q>>2) + 4*g;
        u16 bits = 0;
        if (row < ROWS) {
          int bgl = bg0 + row/JJ;
          if (bgl < Btot)
            bits = f2bf(x0[(size_t)(bgl*JJ + row%JJ)*CC + ccol]);
        }
        pk |= ((u32)bits) << (16*h);
      }
      x0p[mt][qp] = pk;
    }
  }

  // ---- load x, split hi/lo into LDS; zero pad rows ----
  for (int el = tid; el < PP*CC; el += 512) {
    int r = el >> 7, c = el & 127;
    float v = 0.f;
    if (r < ROWS) {
      int bgl = bg0 + r/JJ;
      if (bgl < Btot) v = x[(size_t)(bgl*JJ + r%JJ)*CC + c];
    }
    u16 h = f2bf(v);
    xh[r*XPITCH + c] = h;
    xl[r*XPITCH + c] = f2bf(v - bf2f(h));
  }
  if (tid < 128) {
    int j = tid % JJ;
    diag8[tid] = (tid < ROWS) ? 0.8f * adj[j*JJ + j] : 0.f;
    biasl[tid] = bvec[tid];
  }

  // ---- W-hi fragments into registers (LDS bounce through h1 area) ----
  s8v whi[2][8];
  #pragma unroll
  for (int w01 = 0; w01 < 2; ++w01) {
    const float* Wp = w01 ? W1 : W0;
    __syncthreads();
    for (int el = tid; el < CC*CC; el += 512) h1[el] = Wp[el];
    __syncthreads();
    #pragma unroll
    for (int ks = 0; ks < 8; ++ks) {
      s8v v;
      #pragma unroll
      for (int e = 0; e < 8; ++e) {
        float wv = h1[(ks*16 + 8*g + e)*CC + ccol];
        v[e] = (short)f2bf(wv);
      }
      whi[w01][ks] = v;
    }
  }
  __syncthreads();

  // ---- W-lo chunk staging (split in-kernel, L2-resident source) ----
  auto stage_wlo = [&](int ks, int nb) {
    #pragma unroll
    for (int i = 0; i < 8; ++i) {
      int el = tid + i*512;              // 0..4095
      int w01 = el >> 11, kk = (el >> 7) & 15, n = el & 127;
      const float* Wp = w01 ? W1 : W0;
      float v = Wp[(ks*16 + kk)*CC + n];
      u16 h = f2bf(v);
      wlo[((nb*2 + w01)*128 + n)*WLOP + kk] = f2bf(v - bf2f(h));
    }
  };
  stage_wlo(0, 0);
  __syncthreads();

  // ================= layer loop =================
  #pragma unroll 1
  for (int layer = 0; layer < NLAYERS; ++layer) {
    f16v acc0[2], acc1[2];
    #pragma unroll
    for (int mt = 0; mt < 2; ++mt) {
      #pragma unroll
      for (int i = 0; i < 16; ++i) { acc0[mt][i] = 0.f; acc1[mt][i] = 0.f; }
    }

    // ---- GEMM over K=128, Kstep=16, W-lo double-buffered ----
    #pragma unroll
    for (int ks = 0; ks < 8; ++ks) {
      const int cur = ks & 1;
      float sv[8];
      if (ks < 7) {                       // issue next chunk's global loads early
        #pragma unroll
        for (int i = 0; i < 8; ++i) {
          int el = tid + i*512;
          int w01 = el >> 11, kk = (el >> 7) & 15, n = el & 127;
          const float* Wp = w01 ? W1 : W0;
          sv[i] = Wp[((ks+1)*16 + kk)*CC + n];
        }
      }
      // B-lo fragments for this Kstep
      int b0i = ((cur*2 + 0)*128 + ccol)*WLOP + 8*g;
      int b1i = ((cur*2 + 1)*128 + ccol)*WLOP + 8*g;
      s8v bl0 = cmb(*(const s4v*)&wlo[b0i], *(const s4v*)&wlo[b0i+4]);
      s8v bl1 = cmb(*(const s4v*)&wlo[b1i], *(const s4v*)&wlo[b1i+4]);

      #pragma unroll
      for (int mt = 0; mt < 2; ++mt) {
        int row = (wm*2+mt)*32 + nl;
        int xb = row*XPITCH + ks*16 + 8*g;
        s8v ah = cmb(*(const s4v*)&xh[xb], *(const s4v*)&xh[xb+4]);
        s8v al = cmb(*(const s4v*)&xl[xb], *(const s4v*)&xl[xb+4]);
        acc0[mt] = __builtin_amdgcn_mfma_f32_32x32x16_bf16(ah, whi[0][ks], acc0[mt], 0, 0, 0);
        acc0[mt] = __builtin_amdgcn_mfma_f32_32x32x16_bf16(al, whi[0][ks], acc0[mt], 0, 0, 0);
        acc0[mt] = __builtin_amdgcn_mfma_f32_32x32x16_bf16(ah, bl0,        acc0[mt], 0, 0, 0);
        acc1[mt] = __builtin_amdgcn_mfma_f32_32x32x16_bf16(ah, whi[1][ks], acc1[mt], 0, 0, 0);
        acc1[mt] = __builtin_amdgcn_mfma_f32_32x32x16_bf16(al, whi[1][ks], acc1[mt], 0, 0, 0);
        acc1[mt] = __builtin_amdgcn_mfma_f32_32x32x16_bf16(ah, bl1,        acc1[mt], 0, 0, 0);
      }
      if (ks < 7) {                       // split + write staged chunk
        #pragma unroll
        for (int i = 0; i < 8; ++i) {
          int el = tid + i*512;
          int w01 = el >> 11, kk = (el >> 7) & 15, n = el & 127;
          float v = sv[i];
          u16 h = f2bf(v);
          wlo[(((cur^1)*2 + w01)*128 + n)*WLOP + kk] = f2bf(v - bf2f(h));
        }
      }
      __syncthreads();
    }

    // ---- epilogue: H1 -> LDS ----
    #pragma unroll
    for (int mt = 0; mt < 2; ++mt) {
      #pragma unroll
      for (int q = 0; q < 16; ++q) {
        int row = (wm*2+mt)*32 + (q&3) + 8*(q>>2) + 4*g;
        h1[row*CC + ccol] = acc1[mt][q];
      }
    }
    __syncthreads();

    // ---- joint mix, in place: M1[b,j,:] = sum_{k!=j} 0.8*adj[j,k]*H1[b,k,:] ----
    if (wid < BB) {
      const int rb = wid * JJ;           // wave-uniform b
      f2v h[JJ];
      #pragma unroll
      for (int k = 0; k < JJ; ++k)
        h[k] = *(const f2v*)&h1[(rb+k)*CC + 2*lane];
      for (int j = 0; j < JJ; ++j) {
        f2v m; m.x = 0.f; m.y = 0.f;
        #pragma unroll
        for (int k = 0; k < JJ; ++k) {
          if (k == j) continue;
          float a = 0.8f * adj[j*JJ + k];
          m.x += a * h[k].x; m.y += a * h[k].y;
        }
        *(f2v*)&h1[(rb+j)*CC + 2*lane] = m;
      }
    }
    __syncthreads();

    // ---- final combine: x = 0.2*x0 + 0.8*diag*H0 + M1 + b ; split back to xh/xl ----
    #pragma unroll
    for (int mt = 0; mt < 2; ++mt) {
      #pragma unroll
      for (int q = 0; q < 16; ++q) {
        int row = (wm*2+mt)*32 + (q&3) + 8*(q>>2) + 4*g;
        float x0f = bf2f((u16)(x0p[mt][q>>1] >> (16*(q&1))));
        float xv = 0.2f*x0f + diag8[row]*acc0[mt][q] + h1[row*CC + ccol] + biasl[ccol];
        u16 hh = f2bf(xv);
        xh[row*XPITCH + ccol] = hh;
        xl[row*XPITCH + ccol] = f2bf(xv - bf2f(hh));
      }
    }
    if (layer < NLAYERS-1) stage_wlo(0, 0);
    __syncthreads();
  }

  // ---- LayerNorm + store ----
  float ga = gamma[lane], gb = gamma[lane+64];
  float ba = beta[lane],  bb = beta[lane+64];
  #pragma unroll 1
  for (int i = 0; i < 16; ++i) {
    int r = wid + 8*i;
    if (r >= ROWS) break;                 // wave-uniform
    int bgl = bg0 + r/JJ;
    if (bgl < Btot) {
      int xb = r*XPITCH;
      float xa = bf2f(xh[xb+lane])    + bf2f(xl[xb+lane]);
      float xc = bf2f(xh[xb+64+lane]) + bf2f(xl[xb+64+lane]);
      float mu = wred(xa + xc) * (1.f/128.f);
      float da = xa - mu, dc = xc - mu;
      float vs = wred(da*da + dc*dc) * (1.f/128.f);
      float rs = rsqrtf(vs + 1e-10f);
      size_t ob = (size_t)(bgl*JJ + r%JJ)*CC;
      out[ob + lane]      = da*rs*ga + ba;
      out[ob + 64 + lane] = dc*rs*gb + bb;
    }
  }
}

extern "C" void kernel_launch(void* const* d_in, const int* in_sizes, int n_in,
                              void* d_out, int out_size, void* d_ws, size_t ws_size,
                              hipStream_t stream) {
  const float* x   = (const float*)d_in[0];
  const float* x0  = (const float*)d_in[1];
  const float* adj = (const float*)d_in[2];
  const float* W0  = (const float*)d_in[3];
  const float* W1  = (const float*)d_in[4];
  const float* bv  = (const float*)d_in[5];
  const float* ga  = (const float*)d_in[6];
  const float* be  = (const float*)d_in[7];
  int Btot = in_sizes[0] / (JJ*CC);
  int grid = (Btot + BB - 1) / BB;
  hipFuncSetAttribute((const void*)gconv_fused,
                      hipFuncAttributeMaxDynamicSharedMemorySize, SMEM_BYTES);
  gconv_fused<<<dim3(grid), dim3(512), SMEM_BYTES, stream>>>(
      x, x0, adj, W0, W1, bv, ga, be, (float*)d_out, Btot);
}

// Round 2
// 1477.031 us; speedup vs baseline: 1.4959x; 1.4959x over previous
//
#include <hip/hip_runtime.h>
#include <stdint.h>

typedef unsigned short u16;
typedef unsigned int   u32;
typedef __attribute__((ext_vector_type(4)))  short s4v;
typedef __attribute__((ext_vector_type(8)))  short s8v;
typedef __attribute__((ext_vector_type(16))) float f16v;
typedef __attribute__((ext_vector_type(2)))  float f2v;
typedef __attribute__((ext_vector_type(4)))  float f4v;

#define JJ 17
#define CC 128
#define BB 7
#define ROWS (BB*JJ)     // 119
#define PP 128
#define XP 132           // pitch: 264B rows (8B-aligned, 66 dw -> 2-way bank = free)
#define NLAYERS 5

#define XBUF_BYTES (PP*XP*4)             // 67584: xh u16[128][132] @0, xl @+33792B; h1 f32[128][132] alias; wf32 alias
#define WLO_OFF    XBUF_BYTES
#define WLO_BYTES  (2*PP*XP*2)           // 67584: u16 [2][128][132] (k-pitched)
#define ADJS_OFF   (WLO_OFF + WLO_BYTES) // 135168
#define DIAG_OFF   (ADJS_OFF + 1216)     // 136384
#define BIAS_OFF   (DIAG_OFF + 512)      // 136896
#define LDS_BYTES  (BIAS_OFF + 512)      // 137408

__device__ __forceinline__ u16 f2bf(float f) {
  u32 u = __float_as_uint(f);
  u += 0x7FFFu + ((u >> 16) & 1u);   // RNE
  return (u16)(u >> 16);
}
__device__ __forceinline__ float bf2f(u16 h) {
  return __uint_as_float(((u32)h) << 16);
}
__device__ __forceinline__ s8v cmb(s4v a, s4v b) {
  s8v r;
  r[0]=a[0]; r[1]=a[1]; r[2]=a[2]; r[3]=a[3];
  r[4]=b[0]; r[5]=b[1]; r[6]=b[2]; r[7]=b[3];
  return r;
}
__device__ __forceinline__ float wred(float v) {
  #pragma unroll
  for (int m = 32; m >= 1; m >>= 1) v += __shfl_xor(v, m, 64);
  return v;
}

__global__ void __launch_bounds__(1024)
gconv_fused(const float* __restrict__ x, const float* __restrict__ x0,
            const float* __restrict__ adj, const float* __restrict__ W0,
            const float* __restrict__ W1, const float* __restrict__ bvec,
            const float* __restrict__ gamma, const float* __restrict__ beta,
            float* __restrict__ out, int totRows)
{
  extern __shared__ char smem[];
  u16*   xh    = (u16*)smem;                   // [PP][XP]
  u16*   xl    = xh + PP*XP;
  float* h1    = (float*)smem;                 // alias of xbuf, [PP][XP] f32
  float* wf32  = (float*)smem;                 // alias, flat [16384] f32 (W bounce)
  u16*   wlo   = (u16*)(smem + WLO_OFF);       // [2][PP][XP]
  float* adjs  = (float*)(smem + ADJS_OFF);    // [17*17], 0.8*adj, diag zeroed
  float* diag8 = (float*)(smem + DIAG_OFF);    // [128]
  float* biasl = (float*)(smem + BIAS_OFF);    // [128]

  const int tid  = threadIdx.x;
  const int lane = tid & 63;
  const int wid  = tid >> 6;        // 0..15
  const int wm   = wid >> 2;        // 0..3  M-tile
  const int wn   = wid & 3;         // 0..3  N-tile
  const int g    = lane >> 5;
  const int nl   = lane & 31;
  const int ccol = wn*32 + nl;
  const int grow0 = blockIdx.x * ROWS;   // global row base (rows are consecutive)

  // ---- W prep: bounce f32 through LDS once per W; whi -> regs, wlo -> LDS (resident all layers)
  s8v whi[2][8];
  #pragma unroll
  for (int w01 = 0; w01 < 2; ++w01) {
    const float* Wp = w01 ? W1 : W0;
    if (w01) __syncthreads();
    #pragma unroll
    for (int i = 0; i < 16; ++i) wf32[tid + i*1024] = Wp[tid + i*1024];
    __syncthreads();
    #pragma unroll
    for (int ks = 0; ks < 8; ++ks) {
      s8v v;
      #pragma unroll
      for (int e = 0; e < 8; ++e)
        v[e] = (short)f2bf(wf32[(ks*16 + 8*g + e)*CC + ccol]);
      whi[w01][ks] = v;
    }
    #pragma unroll
    for (int i = 0; i < 16; ++i) {
      int el = tid + i*1024;
      int k = el >> 7, n = el & 127;
      float v = wf32[el];
      u16 h = f2bf(v);
      wlo[(w01*PP + n)*XP + k] = f2bf(v - bf2f(h));
    }
  }
  __syncthreads();   // wf32 (xbuf) free now

  // ---- x -> xh/xl (vectorized), pad rows zero
  #pragma unroll
  for (int i = 0; i < 4; ++i) {
    int el4 = tid + i*1024;          // 4096 float4 = 16384 floats
    int r = el4 >> 5, c4 = (el4 & 31) << 2;
    f4v v; v[0]=0.f; v[1]=0.f; v[2]=0.f; v[3]=0.f;
    if (r < ROWS && (grow0 + r) < totRows)
      v = *(const f4v*)&x[(size_t)(grow0 + r)*CC + c4];
    s4v sh, sl;
    #pragma unroll
    for (int e = 0; e < 4; ++e) {
      u16 hh = f2bf(v[e]);
      sh[e] = (short)hh;
      sl[e] = (short)f2bf(v[e] - bf2f(hh));
    }
    *(s4v*)&xh[r*XP + c4] = sh;
    *(s4v*)&xl[r*XP + c4] = sl;
  }
  if (tid < JJ*JJ) {
    int j = tid / JJ, k = tid - j*JJ;
    adjs[tid] = (j == k) ? 0.f : 0.8f * adj[tid];
  }
  if (tid < PP) {
    int j = tid % JJ;
    diag8[tid] = (tid < ROWS) ? 0.8f * adj[j*JJ + j] : 0.f;
    biasl[tid] = bvec[tid];
  }
  __syncthreads();

  const int arow = wm*32 + nl;

  // ================= layer loop =================
  #pragma unroll 1
  for (int layer = 0; layer < NLAYERS; ++layer) {
    f16v acc0, acc1;
    #pragma unroll
    for (int i = 0; i < 16; ++i) { acc0[i] = 0.f; acc1[i] = 0.f; }

    // ---- GEMM: pure LDS reads + MFMA, no barriers, no global traffic
    #pragma unroll
    for (int ks = 0; ks < 8; ++ks) {
      const int xb = arow*XP + ks*16 + 8*g;
      s8v ah = cmb(*(const s4v*)&xh[xb], *(const s4v*)&xh[xb+4]);
      s8v al = cmb(*(const s4v*)&xl[xb], *(const s4v*)&xl[xb+4]);
      const int bb0 = ccol*XP + ks*16 + 8*g;
      s8v bl0 = cmb(*(const s4v*)&wlo[bb0], *(const s4v*)&wlo[bb0+4]);
      s8v bl1 = cmb(*(const s4v*)&wlo[PP*XP + bb0], *(const s4v*)&wlo[PP*XP + bb0+4]);
      acc0 = __builtin_amdgcn_mfma_f32_32x32x16_bf16(ah, whi[0][ks], acc0, 0, 0, 0);
      acc0 = __builtin_amdgcn_mfma_f32_32x32x16_bf16(al, whi[0][ks], acc0, 0, 0, 0);
      acc0 = __builtin_amdgcn_mfma_f32_32x32x16_bf16(ah, bl0,        acc0, 0, 0, 0);
      acc1 = __builtin_amdgcn_mfma_f32_32x32x16_bf16(ah, whi[1][ks], acc1, 0, 0, 0);
      acc1 = __builtin_amdgcn_mfma_f32_32x32x16_bf16(al, whi[1][ks], acc1, 0, 0, 0);
      acc1 = __builtin_amdgcn_mfma_f32_32x32x16_bf16(ah, bl1,        acc1, 0, 0, 0);
    }
    __syncthreads();               // all xh/xl reads done (h1 aliases them)

    // ---- epilogue: acc1 (X@W1) -> h1
    #pragma unroll
    for (int q = 0; q < 16; ++q) {
      int row = wm*32 + (q&3) + 8*(q>>2) + 4*g;
      h1[row*XP + ccol] = acc1[q];
    }
    __syncthreads();

    // ---- joint mix in place: h1[b,j,:] = sum_k adjs[j,k]*h1[b,k,:]
    if (wid < BB) {
      const int rb = wid * JJ;
      f2v h[JJ];
      #pragma unroll
      for (int k = 0; k < JJ; ++k)
        h[k] = *(const f2v*)&h1[(rb+k)*XP + 2*lane];
      #pragma unroll 1
      for (int j = 0; j < JJ; ++j) {
        f2v m; m.x = 0.f; m.y = 0.f;
        #pragma unroll
        for (int k = 0; k < JJ; ++k) {
          float a = adjs[j*JJ + k];
          m.x += a * h[k].x; m.y += a * h[k].y;
        }
        *(f2v*)&h1[(rb+j)*XP + 2*lane] = m;
      }
    }
    __syncthreads();

    // ---- combine phase A: gather everything into regs
    float tmp[16];
    #pragma unroll
    for (int q = 0; q < 16; ++q) {
      int row = wm*32 + (q&3) + 8*(q>>2) + 4*g;
      int grow = grow0 + row;
      float x0v = (row < ROWS && grow < totRows) ? x0[(size_t)grow*CC + ccol] : 0.f;
      tmp[q] = 0.2f*x0v + diag8[row]*acc0[q] + h1[row*XP + ccol] + biasl[ccol];
    }
    __syncthreads();               // h1 reads done before overwriting as xh/xl

    // ---- combine phase B: write new x split
    #pragma unroll
    for (int q = 0; q < 16; ++q) {
      int row = wm*32 + (q&3) + 8*(q>>2) + 4*g;
      u16 hh = f2bf(tmp[q]);
      xh[row*XP + ccol] = hh;
      xl[row*XP + ccol] = f2bf(tmp[q] - bf2f(hh));
    }
    __syncthreads();
  }

  // ---- LayerNorm + store
  float ga = gamma[lane], g2 = gamma[64+lane];
  float ba = beta[lane],  b2 = beta[64+lane];
  #pragma unroll 1
  for (int i = 0; i < 8; ++i) {
    int r = wid + 16*i;            // 0..127, wave-uniform
    if (r >= ROWS) continue;
    int grow = grow0 + r;
    if (grow >= totRows) continue;
    int xb = r*XP;
    float xa = bf2f(xh[xb+lane])    + bf2f(xl[xb+lane]);
    float xc = bf2f(xh[xb+64+lane]) + bf2f(xl[xb+64+lane]);
    float mu = wred(xa + xc) * (1.f/128.f);
    float da = xa - mu, dc = xc - mu;
    float vs = wred(da*da + dc*dc) * (1.f/128.f);
    float rs = rsqrtf(vs + 1e-10f);
    size_t ob = (size_t)grow*CC;
    out[ob + lane]      = da*rs*ga + ba;
    out[ob + 64 + lane] = dc*rs*g2 + b2;
  }
}

extern "C" void kernel_launch(void* const* d_in, const int* in_sizes, int n_in,
                              void* d_out, int out_size, void* d_ws, size_t ws_size,
                              hipStream_t stream) {
  const float* x   = (const float*)d_in[0];
  const float* x0  = (const float*)d_in[1];
  const float* adj = (const float*)d_in[2];
  const float* W0  = (const float*)d_in[3];
  const float* W1  = (const float*)d_in[4];
  const float* bv  = (const float*)d_in[5];
  const float* ga  = (const float*)d_in[6];
  const float* be  = (const float*)d_in[7];
  int totRows = in_sizes[0] / CC;
  int nBatch  = totRows / JJ;
  int grid    = (nBatch + BB - 1) / BB;
  hipFuncSetAttribute((const void*)gconv_fused,
                      hipFuncAttributeMaxDynamicSharedMemorySize, LDS_BYTES);
  gconv_fused<<<dim3(grid), dim3(1024), LDS_BYTES, stream>>>(
      x, x0, adj, W0, W1, bv, ga, be, (float*)d_out, totRows);
}